// Round 21
// baseline (169.265 us; speedup 1.0000x reference)
//
#include <hip/hip_runtime.h>
#include <hip/hip_bf16.h>

#define DI __device__ __forceinline__

typedef __attribute__((ext_vector_type(4))) float f32x4;
typedef __attribute__((ext_vector_type(8))) short s16x8;
typedef __attribute__((ext_vector_type(4))) short s16x4;

static constexpr int BB = 2, SS = 2048, DD = 1024, HH = 16;
static constexpr int LDQ = 3 * DD; // QKV packed row stride
static constexpr size_t TOK = (size_t)BB * SS;
static constexpr float ALPHA2 = 0.125f * 1.4426950408889634f; // 1/sqrt(dk) * log2(e)

DI float b2f(short s) { union { float f; unsigned u; } c; c.u = ((unsigned)(unsigned short)s) << 16; return c.f; }
DI short f2b(float f) { union { float f; unsigned u; } c; c.f = f; unsigned r = c.u + 0x7FFFu + ((c.u >> 16) & 1u); return (short)(r >> 16); }

DI void async16(void* lds, const void* g) {
  __builtin_amdgcn_global_load_lds((const __attribute__((address_space(1))) unsigned int*)g,
                                   (__attribute__((address_space(3))) unsigned int*)lds, 16, 0, 0);
}
DI f32x4 mfma16(s16x8 a, s16x8 b, f32x4 c) { return __builtin_amdgcn_mfma_f32_16x16x32_bf16(a, b, c, 0, 0, 0); }

// ---------------- fused prep: casts + bias concat + prev_eta transpose + band zero (one launch) ----------------
DI void cast8(const float* __restrict__ in, short* __restrict__ out, int idx) {
  int i = idx * 8;
  float4 a = *(const float4*)(in + i);
  float4 b = *(const float4*)(in + i + 4);
  s16x8 o;
  o[0]=f2b(a.x); o[1]=f2b(a.y); o[2]=f2b(a.z); o[3]=f2b(a.w);
  o[4]=f2b(b.x); o[5]=f2b(b.y); o[6]=f2b(b.z); o[7]=f2b(b.w);
  *(s16x8*)(out + i) = o;
}
__global__ __launch_bounds__(256) void prep2_k(
    const float* __restrict__ x,
    const float* __restrict__ Wq, const float* __restrict__ Wk,
    const float* __restrict__ Wv, const float* __restrict__ Wo,
    const float* __restrict__ bq, const float* __restrict__ bk, const float* __restrict__ bv,
    const float* __restrict__ prev_eta,
    short* __restrict__ Xb, short* __restrict__ Wcat, short* __restrict__ Wob,
    float* __restrict__ bcat, short* __restrict__ peT, short* __restrict__ etaL)
{
  __shared__ float t[64][65];
  int bid = blockIdx.x, tid = threadIdx.x;
  if (bid < 2048)      { cast8(x,  Xb,                         bid * 256 + tid); return; }
  if (bid < 2560)      { cast8(Wq, Wcat,                      (bid - 2048) * 256 + tid); return; }
  if (bid < 3072)      { cast8(Wk, Wcat + (size_t)DD * DD,    (bid - 2560) * 256 + tid); return; }
  if (bid < 3584)      { cast8(Wv, Wcat + (size_t)2 * DD * DD,(bid - 3072) * 256 + tid); return; }
  if (bid < 4096)      { cast8(Wo, Wob,                       (bid - 3584) * 256 + tid); return; }
  if (bid < 4108) {
    int i = (bid - 4096) * 256 + tid;
    if (i < DD) bcat[i] = bq[i];
    else if (i < 2 * DD) bcat[i] = bk[i - DD];
    else if (i < 3 * DD) bcat[i] = bv[i - 2 * DD];
    return;
  }
  if (bid < 6156) {
    int idx = bid - 4108;
    int bz = idx >> 10, rem = idx & 1023, cy = rem >> 5, cx = rem & 31;
    const float* src = prev_eta + (size_t)bz * SS * SS;
    short* dst = peT + (size_t)bz * SS * SS;
    int r0 = cy * 64, c0 = cx * 64;
    #pragma unroll
    for (int p = 0; p < 4; ++p) {
      int id2 = tid + p * 256, r = id2 >> 4, c4 = (id2 & 15) << 2;
      float4 v = *(const float4*)(src + (size_t)(r0 + r) * SS + c0 + c4);
      t[r][c4] = v.x; t[r][c4+1] = v.y; t[r][c4+2] = v.z; t[r][c4+3] = v.w;
    }
    __syncthreads();
    #pragma unroll
    for (int p = 0; p < 4; ++p) {
      int id2 = tid + p * 256, c = id2 >> 4, r4 = (id2 & 15) << 2;
      s16x4 o;
      o[0] = f2b(t[r4][c]); o[1] = f2b(t[r4+1][c]); o[2] = f2b(t[r4+2][c]); o[3] = f2b(t[r4+3][c]);
      *(s16x4*)(dst + (size_t)(c0 + c) * SS + r0 + r4) = o;
    }
    return;
  }
  // band zero: the 64x64 region above each even diagonal tile of etaL
  {
    int idx = bid - 6156;
    int u = idx & 15, b = idx >> 4;
    int q0 = u * 128, c0 = q0 + 64;
    size_t base = (size_t)b * SS * SS;
    int r = tid >> 2, c = (tid & 3) * 16;
    s16x8 z = {};
    *(s16x8*)(etaL + base + (size_t)(q0 + r) * SS + c0 + c) = z;
    *(s16x8*)(etaL + base + (size_t)(q0 + r) * SS + c0 + c + 8) = z;
  }
}

// ---------------- transpose V per (b,h) + fused ||v||_2 ----------------
__global__ __launch_bounds__(256) void transpose_v_k(const short* __restrict__ Vq, short* __restrict__ Vt,
                                                     float* __restrict__ vmag) {
  __shared__ short t[64][72];
  int bh = blockIdx.y, s0 = blockIdx.x * 64;
  int b = bh >> 4, h = bh & 15;
  const short* src = Vq + ((size_t)(b * SS + s0)) * LDQ + h * 64;
  short* dst = Vt + ((size_t)bh * 64) * SS + s0;
  int tid = threadIdx.x;
  #pragma unroll
  for (int p = 0; p < 2; ++p) {
    int idx = tid + p * 256, r = idx >> 3, c8 = (idx & 7) << 3;
    s16x8 v = *(const s16x8*)(src + (size_t)r * LDQ + c8);
    *(s16x8*)&t[r][c8] = v;
  }
  __syncthreads();
  #pragma unroll
  for (int p = 0; p < 2; ++p) {
    int idx = tid + p * 256, d = idx >> 3, s8 = (idx & 7) << 3;
    s16x8 o;
    #pragma unroll
    for (int j = 0; j < 8; ++j) o[j] = t[s8 + j][d];
    *(s16x8*)(dst + (size_t)d * SS + s8) = o;
  }
  int row = tid >> 2, part = tid & 3;
  float acc = 0.f;
  #pragma unroll
  for (int j = 0; j < 16; ++j) { float v = b2f(t[row][part * 16 + j]); acc += v * v; }
  acc += __shfl_xor(acc, 1);
  acc += __shfl_xor(acc, 2);
  if (part == 0) vmag[(size_t)bh * SS + s0 + row] = sqrtf(acc);
}

// ---------------- QKV GEMM (R13-proven): 128x128 tile, BK=32, 8 waves, XCD-swizzled ----------------
__global__ __launch_bounds__(512) void gemm_qkv_k(
    const short* __restrict__ A, const short* __restrict__ Bt, short* __restrict__ C,
    const float* __restrict__ bias, int M, int N, int K)
{
  __shared__ short As[2][128 * 32];
  __shared__ short Bs[2][128 * 32];
  int bx = blockIdx.x, by = blockIdx.y;
  {
    int lin = bx + gridDim.x * by;
    int nwg = gridDim.x * gridDim.y;
    int q = nwg >> 3;
    int sw = (lin & 7) * q + (lin >> 3);
    bx = sw % gridDim.x; by = sw / gridDim.x;
  }
  int m0 = by * 128, n0 = bx * 128;
  int tid = threadIdx.x, w = tid >> 6, l = tid & 63;
  int wm = w >> 2, wn = w & 3;
  f32x4 acc[4][2] = {};
  const int scol = ((l & 3) ^ ((l >> 3) & 3)) * 8;
  const short* aSrc = A + (size_t)(m0 + w * 16 + (l >> 2)) * K + scol;
  const short* bSrc = Bt + (size_t)(n0 + w * 16 + (l >> 2)) * K + scol;
  int ar = wm * 64 + (l & 15);
  int br = wn * 32 + (l & 15);
  const int koffr = ((l >> 4) ^ ((l >> 1) & 3)) * 8;
  auto STAGE = [&](int buf, int k0) {
    async16(&As[buf][w * 512], aSrc + k0);
    async16(&Bs[buf][w * 512], bSrc + k0);
  };
  STAGE(0, 0);
  int cur = 0;
  for (int k0 = 0; k0 < K; k0 += 32) {
    __syncthreads();
    if (k0 + 32 < K) STAGE(cur ^ 1, k0 + 32);
    const short* AB = As[cur];
    const short* BBs = Bs[cur];
    s16x8 af[4], bfr[2];
    #pragma unroll
    for (int m = 0; m < 4; ++m) af[m] = *(const s16x8*)(AB + (ar + m * 16) * 32 + koffr);
    #pragma unroll
    for (int n = 0; n < 2; ++n) bfr[n] = *(const s16x8*)(BBs + (br + n * 16) * 32 + koffr);
    __builtin_amdgcn_s_setprio(1);
    #pragma unroll
    for (int m = 0; m < 4; ++m)
      #pragma unroll
      for (int n = 0; n < 2; ++n)
        acc[m][n] = mfma16(af[m], bfr[n], acc[m][n]);
    __builtin_amdgcn_s_setprio(0);
    cur ^= 1;
  }
  int wr = m0 + wm * 64, wc = n0 + wn * 32;
  int rsub = (l >> 4) * 4, csub = l & 15;
  #pragma unroll
  for (int m = 0; m < 4; ++m)
    #pragma unroll
    for (int n = 0; n < 2; ++n) {
      int col = wc + n * 16 + csub;
      float bv = bias[col];
      #pragma unroll
      for (int r = 0; r < 4; ++r) {
        int row = wr + m * 16 + rsub + r;
        C[(size_t)row * N + col] = f2b(acc[m][n][r] + bv);
      }
    }
}

// ---------------- 64-col 8-wave GEMM body, BK=64, async16 double-buffered (R17-proven) ----------------
template<bool HAS_BIAS>
DI void gemm64(const short* __restrict__ A, const short* __restrict__ B,
               float* __restrict__ C, const float* __restrict__ bias,
               int m0, int n0, int kmax, int K, int N,
               short (*As)[128 * 64], short (*Bs)[64 * 64], int tid)
{
  int w = tid >> 6, l = tid & 63;
  int wm = w >> 2, wn = w & 3;
  f32x4 acc[4] = {};
  const int swz = ((l & 7) ^ ((l >> 3) & 7)) * 8;
  const short* aSrc = A + (size_t)(m0 + w * 16 + (l >> 3)) * K + swz;
  const short* bSrc = B + (size_t)(n0 + w * 8 + (l >> 3)) * K + swz;
  int ar = wm * 64 + (l & 15);
  int br = wn * 16 + (l & 15);
  const int c0 = (((l >> 4) + 0) ^ (l & 7)) * 8;
  const int c1 = (((l >> 4) + 4) ^ (l & 7)) * 8;
  auto STAGE = [&](int buf, int k0) {
    async16(&As[buf][(2 * w) * 512],     aSrc + k0);
    async16(&As[buf][(2 * w + 1) * 512], aSrc + (size_t)8 * K + k0);
    async16(&Bs[buf][w * 512],           bSrc + k0);
  };
  __syncthreads();              // guard LDS reuse across phases
  STAGE(0, 0);
  int cur = 0;
  for (int k0 = 0; k0 < kmax; k0 += 64) {
    __syncthreads();
    if (k0 + 64 < kmax) STAGE(cur ^ 1, k0 + 64);
    const short* AB = As[cur];
    const short* BBs = Bs[cur];
    s16x8 af0[4], af1[4];
    #pragma unroll
    for (int m = 0; m < 4; ++m) {
      af0[m] = *(const s16x8*)(AB + (ar + m * 16) * 64 + c0);
      af1[m] = *(const s16x8*)(AB + (ar + m * 16) * 64 + c1);
    }
    s16x8 bf0 = *(const s16x8*)(BBs + br * 64 + c0);
    s16x8 bf1 = *(const s16x8*)(BBs + br * 64 + c1);
    __builtin_amdgcn_s_setprio(1);
    #pragma unroll
    for (int m = 0; m < 4; ++m) acc[m] = mfma16(af0[m], bf0, acc[m]);
    #pragma unroll
    for (int m = 0; m < 4; ++m) acc[m] = mfma16(af1[m], bf1, acc[m]);
    __builtin_amdgcn_s_setprio(0);
    cur ^= 1;
  }
  int wr = m0 + wm * 64, wc = n0 + wn * 16;
  int rsub = (l >> 4) * 4, csub = l & 15;
  int col = wc + csub;
  float bv = HAS_BIAS ? bias[col] : 0.f;
  #pragma unroll
  for (int m = 0; m < 4; ++m)
    #pragma unroll
    for (int r = 0; r < 4; ++r) {
      int row = wr + m * 16 + rsub + r;
      C[(size_t)row * N + col] = acc[m][r] + bv;
    }
}

// ---------------- tail: fused {causal eta GEMM} + {output projection}, XCD-chunked swizzle ----------------
// Same-by blocks share the A/weight panel; chunked remap lin=(orig&7)*64+(orig>>3) keeps each
// XCD on 2 complete by-groups -> shared panels are fetched once per XCD instead of 8x.
__global__ __launch_bounds__(512) void tail_k(
    const short* __restrict__ etaL, const short* __restrict__ peT, float* __restrict__ out1,
    const short* __restrict__ Om, const short* __restrict__ Wob, float* __restrict__ out0,
    const float* __restrict__ bo)
{
  __shared__ short As[2][128 * 64];
  __shared__ short Bs[2][64 * 64];
  int tid = threadIdx.x;
  int orig = blockIdx.x + 32 * blockIdx.y;       // 512 blocks per z-plane
  int lin = (orig & 7) * 64 + (orig >> 3);       // bijective: 512 = 8 * 64
  int bx = lin & 31, by = lin >> 5;
  if (blockIdx.z == 0) {
    int b = by & 1, p = by >> 1;
    int n0 = bx * 64;
    const short* A = etaL + (size_t)b * SS * SS;
    const short* B = peT + (size_t)b * SS * SS;
    float* C = out1 + (size_t)b * SS * SS;
    gemm64<false>(A, B, C, nullptr, p * 128, n0, (p + 1) * 128, SS, SS, As, Bs, tid);
    gemm64<false>(A, B, C, nullptr, (15 - p) * 128, n0, (16 - p) * 128, SS, SS, As, Bs, tid);
  } else {
    gemm64<true>(Om, Wob, out0, bo, bx * 128, by * 64, DD, DD, DD, As, Bs, tid);
  }
}

// ---------------- flash attention fwd: swapped QK^T, fixed-m, split-K, reg-staged K/V dbuf (80 KB, 1 barrier/iter) ----------------
__global__ __launch_bounds__(512) void flash_k(
    const short* __restrict__ Q, const short* __restrict__ Kk, const short* __restrict__ Vt,
    short* __restrict__ Om, float* __restrict__ lstat)
{
  __shared__ short Ks[2][2][64 * 64];   // [group][buf]
  __shared__ short Vs[2][2][64 * 64];
  __shared__ short Ps[8][16 * 64];
  int bh = blockIdx.x, p = blockIdx.y;
  int b = bh >> 4, h = bh & 15;
  int tid = threadIdx.x, w = tid >> 6, l = tid & 63;
  int g = w >> 2, wq = w & 3;
  int qtB = 31 - p;
  int myqt = g ? qtB : p;
  int koff = (l >> 4) * 8;
  const short* qbase = Q + ((size_t)(b * SS)) * LDQ + h * 64 + koff;
  int qrow = myqt * 64 + wq * 16 + (l & 15);
  s16x8 aq0 = *(const s16x8*)(qbase + (size_t)qrow * LDQ);
  s16x8 aq1 = *(const s16x8*)(qbase + (size_t)qrow * LDQ + 32);
  s16x8 onesf;
  #pragma unroll
  for (int j = 0; j < 8; ++j) onesf[j] = (short)0x3F80;  // bf16 1.0
  f32x4 o[4] = {};
  f32x4 lacc = {};
  const int swz = ((l & 7) ^ (l >> 3)) * 8;
  const short* kSrc = Kk + ((size_t)(b * SS) + wq * 16 + (l >> 3)) * LDQ + h * 64 + swz;
  const short* vSrc = Vt + ((size_t)bh * 64 + wq * 16 + (l >> 3)) * SS + swz;
  const int c0 = (((l >> 4) + 0) ^ (l & 7)) * 8;
  const int c1 = (((l >> 4) + 4) ^ (l & 7)) * 8;
  const int prow = l & 15;
  const int pwithin = ((l >> 4) & 1) * 4;
  auto tileof = [&](int it) { return g == 0 ? it : (it <= p ? it : 15 + it - p); };
  s16x8 kr0, kr1, vr0, vr1;
  auto LOADR = [&](int t) {
    kr0 = *(const s16x8*)(kSrc + (size_t)t * 64 * LDQ);
    kr1 = *(const s16x8*)(kSrc + (size_t)t * 64 * LDQ + (size_t)8 * LDQ);
    vr0 = *(const s16x8*)(vSrc + t * 64);
    vr1 = *(const s16x8*)(vSrc + t * 64 + (size_t)8 * SS);
  };
  auto WRITE = [&](int buf) {
    *(s16x8*)&Ks[g][buf][(2 * wq) * 512 + l * 8]     = kr0;
    *(s16x8*)&Ks[g][buf][(2 * wq + 1) * 512 + l * 8] = kr1;
    *(s16x8*)&Vs[g][buf][(2 * wq) * 512 + l * 8]     = vr0;
    *(s16x8*)&Vs[g][buf][(2 * wq + 1) * 512 + l * 8] = vr1;
  };
  const int nit = g ? 17 : 16;
  LOADR(tileof(0));
  WRITE(0);
  if (nit > 1) LOADR(tileof(1));
  __syncthreads();
  int cur = 0;
  for (int it = 0; it < 17; ++it) {
    if (it < nit) {
      if (it + 1 < nit) {
        WRITE(cur ^ 1);
        if (it + 2 < nit) LOADR(tileof(it + 2));
      }
      int t = tileof(it);
      const short* KB = Ks[g][cur];
      const short* VB = Vs[g][cur];
      f32x4 s[4] = {};
      __builtin_amdgcn_s_setprio(1);
      #pragma unroll
      for (int n = 0; n < 4; ++n) {
        int row = n * 16 + (l & 15);
        s16x8 bk0 = *(const s16x8*)(KB + row * 64 + c0);
        s16x8 bk1 = *(const s16x8*)(KB + row * 64 + c1);
        s[n] = mfma16(bk0, aq0, s[n]);   // swapped: D[kv][q]
        s[n] = mfma16(bk1, aq1, s[n]);
      }
      __builtin_amdgcn_s_setprio(0);
      if (t == myqt) {     // diagonal tile: causal mask (S^T indices)
        int ql = wq * 16 + (l & 15);
        #pragma unroll
        for (int n = 0; n < 4; ++n)
          #pragma unroll
          for (int r = 0; r < 4; ++r) {
            int kv = n * 16 + (l >> 4) * 4 + r;
            if (kv > ql) s[n][r] = -1e30f;
          }
      }
      #pragma unroll
      for (int n = 0; n < 4; ++n) {
        short* dst = &Ps[w][prow * 64 + (((2 * n + ((l >> 4) >> 1)) ^ (l & 7)) << 3) + pwithin];
        #pragma unroll
        for (int r = 0; r < 4; ++r)
          dst[r] = f2b(__builtin_amdgcn_exp2f(__builtin_fmaf(s[n][r], ALPHA2, -8.0f)));
      }
      __builtin_amdgcn_s_setprio(1);
      #pragma unroll
      for (int st = 0; st < 2; ++st) {
        int pc = (((st * 4) + (l >> 4)) ^ (l & 7)) * 8;
        s16x8 ap = *(const s16x8*)(&Ps[w][(l & 15) * 64 + pc]);
        lacc = mfma16(ap, onesf, lacc);          // row-sum of P via matrix pipe
        #pragma unroll
        for (int n = 0; n < 4; ++n) {
          int row = n * 16 + (l & 15);
          s16x8 bv = *(const s16x8*)(VB + row * 64 + pc);
          o[n] = mfma16(ap, bv, o[n]);
        }
      }
      __builtin_amdgcn_s_setprio(0);
      if (g == 0 && it == p) {
        #pragma unroll
        for (int r = 0; r < 4; ++r) {
          float inv = 1.0f / lacc[r];
          int qr = p * 64 + wq * 16 + (l >> 4) * 4 + r;
          #pragma unroll
          for (int n = 0; n < 4; ++n)
            Om[((size_t)(b * SS + qr)) * DD + h * 64 + n * 16 + (l & 15)] = f2b(o[n][r] * inv);
          if ((l & 15) == 0) lstat[(size_t)bh * SS + qr] = lacc[r];
        }
        #pragma unroll
        for (int n = 0; n < 4; ++n) o[n] = f32x4{0.f, 0.f, 0.f, 0.f};
        lacc = f32x4{0.f, 0.f, 0.f, 0.f};
        myqt = qtB;
        qrow = qtB * 64 + wq * 16 + (l & 15);
        aq0 = *(const s16x8*)(qbase + (size_t)qrow * LDQ);
        aq1 = *(const s16x8*)(qbase + (size_t)qrow * LDQ + 32);
      }
    }
    __syncthreads();   // single barrier: publishes buf[cur^1] writes, retires buf[cur] reads
    cur ^= 1;
  }
  float* Oex = (float*)&Ks[0][0][0];   // 16 KB = group-0's two K buffers (retired)
  float* Lex = (float*)&Vs[0][0][0];
  if (g == 0) {
    #pragma unroll
    for (int n = 0; n < 4; ++n)
      #pragma unroll
      for (int r = 0; r < 4; ++r)
        Oex[wq * 1024 + ((l >> 4) * 4 + r) * 64 + n * 16 + (l & 15)] = o[n][r];
    #pragma unroll
    for (int r = 0; r < 4; ++r)
      Lex[wq * 64 + (l >> 4) * 4 + r] = lacc[r];
  }
  __syncthreads();
  if (g == 1) {
    #pragma unroll
    for (int r = 0; r < 4; ++r) {
      float lt = lacc[r] + Lex[wq * 64 + (l >> 4) * 4 + r];
      float inv = 1.0f / lt;
      int qr = qtB * 64 + wq * 16 + (l >> 4) * 4 + r;
      #pragma unroll
      for (int n = 0; n < 4; ++n) {
        float ot = o[n][r] + Oex[wq * 1024 + ((l >> 4) * 4 + r) * 64 + n * 16 + (l & 15)];
        Om[((size_t)(b * SS + qr)) * DD + h * 64 + n * 16 + (l & 15)] = f2b(ot * inv);
      }
      if ((l & 15) == 0) lstat[(size_t)bh * SS + qr] = lt;
    }
  }
}

// ---------------- eta_layer (A' = I + eta_layer): T14 reg-staged, XCD-chunked swizzle ----------------
__global__ __launch_bounds__(256) void eta_k(
    const short* __restrict__ Q, const short* __restrict__ Kk,
    const float* __restrict__ lstat, const float* __restrict__ vmag, short* __restrict__ etaL)
{
  __shared__ short Ks[64 * 128];
  __shared__ float lrlL[16][64], lvmL[16][64];
  int orig = blockIdx.x, b = blockIdx.y;
  int idx = (orig & 7) * 66 + (orig >> 3);   // bijective: 528 = 8 * 66; same-qt blocks -> same XCD
  int qt = (int)((sqrtf(8.f * idx + 1.f) - 1.f) * 0.5f);
  while ((qt + 1) * (qt + 2) / 2 <= idx) ++qt;
  while (qt * (qt + 1) / 2 > idx) --qt;
  int kt = idx - qt * (qt + 1) / 2;
  int q0 = qt * 64, k0 = kt * 64;
  bool diag = (kt == qt);
  int tid = threadIdx.x, w = tid >> 6, l = tid & 63;
  int qrA = q0 + w * 16 + (l & 15);
  f32x4 eta[4] = {};
  const short* kRow[4];
  #pragma unroll
  for (int j = 0; j < 4; ++j) {
    int rj = (4 * w + j) * 4 + (l >> 4);
    int kp = (l & 8) | ((l & 7) ^ (rj & 7));
    kRow[j] = Kk + ((size_t)(b * SS + k0 + rj)) * LDQ + kp * 8;
  }
  s16x8 kreg[4];
  #pragma unroll
  for (int j = 0; j < 4; ++j) kreg[j] = *(const s16x8*)(kRow[j]);   // head-pair 0
  {
    int hh = tid >> 4, jj = (tid & 15) * 4;
    size_t base = (size_t)(b * HH + hh) * SS;
    float4 lv = *(const float4*)(lstat + base + q0 + jj);
    float4 rv;
    rv.x = -__log2f(lv.x) - 8.f; rv.y = -__log2f(lv.y) - 8.f;
    rv.z = -__log2f(lv.z) - 8.f; rv.w = -__log2f(lv.w) - 8.f;
    *(float4*)&lrlL[hh][jj] = rv;
    float4 vv = *(const float4*)(vmag + base + k0 + jj);
    float4 wv;
    wv.x = __log2f(vv.x); wv.y = __log2f(vv.y);
    wv.z = __log2f(vv.z); wv.w = __log2f(vv.w);
    *(float4*)&lvmL[hh][jj] = wv;
  }
  const short* qbase = Q + ((size_t)(b * SS + qrA)) * LDQ + (l >> 4) * 8;
  s16x8 aq0 = *(const s16x8*)(qbase);        // head 0 fragments
  s16x8 aq1 = *(const s16x8*)(qbase + 32);
  for (int hp = 0; hp < 8; ++hp) {
    __syncthreads();                         // prior phase's Ks reads complete
    #pragma unroll
    for (int j = 0; j < 4; ++j)
      *(s16x8*)&Ks[(w * 4 + j) * 512 + l * 8] = kreg[j];
    if (hp < 7) {
      #pragma unroll
      for (int j = 0; j < 4; ++j) kreg[j] = *(const s16x8*)(kRow[j] + (hp + 1) * 128);
    }
    __syncthreads();                         // Ks ready
    #pragma unroll
    for (int hd = 0; hd < 2; ++hd) {
      int h = 2 * hp + hd;
      s16x8 nq0 = aq0, nq1 = aq1;
      if (h < 15) {
        nq0 = *(const s16x8*)(qbase + (h + 1) * 64);
        nq1 = *(const s16x8*)(qbase + (h + 1) * 64 + 32);
      }
      const int cc0 = (hd * 8 + ((l >> 4) ^ (l & 7))) * 8;
      const int cc1 = (hd * 8 + (((l >> 4) + 4) ^ (l & 7))) * 8;
      f32x4 s[4] = {};
      __builtin_amdgcn_s_setprio(1);
      #pragma unroll
      for (int n = 0; n < 4; ++n) {
        int row = n * 16 + (l & 15);
        s16x8 bk0 = *(const s16x8*)(Ks + row * 128 + cc0);
        s16x8 bk1 = *(const s16x8*)(Ks + row * 128 + cc1);
        s[n] = mfma16(aq0, bk0, s[n]);
        s[n] = mfma16(aq1, bk1, s[n]);
      }
      __builtin_amdgcn_s_setprio(0);
      float rl[4];
      #pragma unroll
      for (int r = 0; r < 4; ++r) rl[r] = lrlL[h][w * 16 + (l >> 4) * 4 + r];
      #pragma unroll
      for (int n = 0; n < 4; ++n) {
        float vm = lvmL[h][n * 16 + (l & 15)];
        #pragma unroll
        for (int r = 0; r < 4; ++r) {
          float pr = __builtin_amdgcn_exp2f(__builtin_fmaf(s[n][r], ALPHA2, vm + rl[r]));
          if (diag) {
            int kv = k0 + n * 16 + (l & 15), qr = q0 + w * 16 + (l >> 4) * 4 + r;
            if (kv > qr) pr = 0.f;
          }
          eta[n][r] += pr;
        }
      }
      aq0 = nq0; aq1 = nq1;
    }
  }
  #pragma unroll
  for (int n = 0; n < 4; ++n) {
    int kv = k0 + n * 16 + (l & 15);
    #pragma unroll
    for (int r = 0; r < 4; ++r) {
      int qr = q0 + w * 16 + (l >> 4) * 4 + r;
      float v = eta[n][r];
      if (diag && kv == qr) v += 1.0f;   // A' = I + eta_layer (residual folded into GEMM)
      etaL[((size_t)(b * SS + qr)) * SS + kv] = f2b(v);
    }
  }
}

extern "C" void kernel_launch(void* const* d_in, const int* in_sizes, int n_in,
                              void* d_out, int out_size, void* d_ws, size_t ws_size,
                              hipStream_t stream) {
  const float* x        = (const float*)d_in[0];
  const float* prev_eta = (const float*)d_in[1];
  const float* Wq = (const float*)d_in[3];
  const float* bq = (const float*)d_in[4];
  const float* Wk = (const float*)d_in[5];
  const float* bk = (const float*)d_in[6];
  const float* Wv = (const float*)d_in[7];
  const float* bv = (const float*)d_in[8];
  const float* Wo = (const float*)d_in[9];
  const float* bo = (const float*)d_in[10];
  float* out0 = (float*)d_out;
  float* out1 = out0 + TOK * DD;

  char* p = (char*)d_ws;
  auto alloc = [&](size_t bytes) { char* r = p; p += (bytes + 255) & ~(size_t)255; return r; };
  short* Xb   = (short*)alloc(TOK * DD * 2);
  short* Wcat = (short*)alloc((size_t)3 * DD * DD * 2);
  short* Wob  = (short*)alloc((size_t)DD * DD * 2);
  float* bcat = (float*)alloc((size_t)3 * DD * 4);
  short* QKV  = (short*)alloc(TOK * (size_t)LDQ * 2);
  short* Vtb  = (short*)alloc(TOK * DD * 2);
  short* Om   = (short*)alloc(TOK * DD * 2);
  short* peT  = (short*)alloc((size_t)BB * SS * SS * 2);
  short* etaL = (short*)alloc((size_t)BB * SS * SS * 2);
  float* lst  = (float*)alloc((size_t)BB * HH * SS * 4);
  float* vmg  = (float*)alloc((size_t)BB * HH * SS * 4);

  // 1) single fused prep launch (casts + biases + prev_eta transpose + band zero)
  prep2_k<<<6188, 256, 0, stream>>>(x, Wq, Wk, Wv, Wo, bq, bk, bv, prev_eta,
                                    Xb, Wcat, Wob, bcat, peT, etaL);

  // 2) fused QKV projection: BK=32, 8-wave blocks (R13-proven), XCD-swizzled (nwg=768)
  gemm_qkv_k<<<dim3(3 * DD / 128, TOK / 128, 1), 512, 0, stream>>>(
      Xb, Wcat, QKV, bcat, (int)TOK, 3 * DD, DD);

  // 3) V transpose + fused ||v||
  transpose_v_k<<<dim3(SS / 64, BB * HH), 256, 0, stream>>>(QKV + 2 * DD, Vtb, vmg);

  // 4) flash attention + l stats (split-K, swapped QK^T, reg-staged K/V dbuf, 1 barrier/iter)
  flash_k<<<dim3(32, 16), 512, 0, stream>>>(QKV, QKV + DD, Vtb, Om, lst);

  // 5) eta_layer (A' = I + eta_layer), T14 reg-staged, XCD-chunked swizzle
  eta_k<<<dim3(528, BB), 256, 0, stream>>>(QKV, QKV + DD, lst, vmg, etaL);

  // 6+7) fused tail: causal eta GEMM + output projection, XCD-chunked swizzle
  tail_k<<<dim3(32, 16, 2), 512, 0, stream>>>(etaL, peT, out1, Om, Wob, out0, bo);
}

// Round 22
// 153.910 us; speedup vs baseline: 1.0998x; 1.0998x over previous
//
#include <hip/hip_runtime.h>
#include <hip/hip_bf16.h>

#define DI __device__ __forceinline__

typedef __attribute__((ext_vector_type(4))) float f32x4;
typedef __attribute__((ext_vector_type(8))) short s16x8;
typedef __attribute__((ext_vector_type(4))) short s16x4;

static constexpr int BB = 2, SS = 2048, DD = 1024, HH = 16;
static constexpr int LDQ = 3 * DD; // QKV packed row stride
static constexpr size_t TOK = (size_t)BB * SS;
static constexpr float ALPHA2 = 0.125f * 1.4426950408889634f; // 1/sqrt(dk) * log2(e)

DI float b2f(short s) { union { float f; unsigned u; } c; c.u = ((unsigned)(unsigned short)s) << 16; return c.f; }
DI short f2b(float f) { union { float f; unsigned u; } c; c.f = f; unsigned r = c.u + 0x7FFFu + ((c.u >> 16) & 1u); return (short)(r >> 16); }

DI void async16(void* lds, const void* g) {
  __builtin_amdgcn_global_load_lds((const __attribute__((address_space(1))) unsigned int*)g,
                                   (__attribute__((address_space(3))) unsigned int*)lds, 16, 0, 0);
}
DI f32x4 mfma16(s16x8 a, s16x8 b, f32x4 c) { return __builtin_amdgcn_mfma_f32_16x16x32_bf16(a, b, c, 0, 0, 0); }

// ---------------- fused prep: casts + bias concat + prev_eta transpose + band zero (one launch) ----------------
DI void cast8(const float* __restrict__ in, short* __restrict__ out, int idx) {
  int i = idx * 8;
  float4 a = *(const float4*)(in + i);
  float4 b = *(const float4*)(in + i + 4);
  s16x8 o;
  o[0]=f2b(a.x); o[1]=f2b(a.y); o[2]=f2b(a.z); o[3]=f2b(a.w);
  o[4]=f2b(b.x); o[5]=f2b(b.y); o[6]=f2b(b.z); o[7]=f2b(b.w);
  *(s16x8*)(out + i) = o;
}
__global__ __launch_bounds__(256) void prep2_k(
    const float* __restrict__ x,
    const float* __restrict__ Wq, const float* __restrict__ Wk,
    const float* __restrict__ Wv, const float* __restrict__ Wo,
    const float* __restrict__ bq, const float* __restrict__ bk, const float* __restrict__ bv,
    const float* __restrict__ prev_eta,
    short* __restrict__ Xb, short* __restrict__ Wcat, short* __restrict__ Wob,
    float* __restrict__ bcat, short* __restrict__ peT, short* __restrict__ etaL)
{
  __shared__ float t[64][65];
  int bid = blockIdx.x, tid = threadIdx.x;
  if (bid < 2048)      { cast8(x,  Xb,                         bid * 256 + tid); return; }
  if (bid < 2560)      { cast8(Wq, Wcat,                      (bid - 2048) * 256 + tid); return; }
  if (bid < 3072)      { cast8(Wk, Wcat + (size_t)DD * DD,    (bid - 2560) * 256 + tid); return; }
  if (bid < 3584)      { cast8(Wv, Wcat + (size_t)2 * DD * DD,(bid - 3072) * 256 + tid); return; }
  if (bid < 4096)      { cast8(Wo, Wob,                       (bid - 3584) * 256 + tid); return; }
  if (bid < 4108) {
    int i = (bid - 4096) * 256 + tid;
    if (i < DD) bcat[i] = bq[i];
    else if (i < 2 * DD) bcat[i] = bk[i - DD];
    else if (i < 3 * DD) bcat[i] = bv[i - 2 * DD];
    return;
  }
  if (bid < 6156) {
    int idx = bid - 4108;
    int bz = idx >> 10, rem = idx & 1023, cy = rem >> 5, cx = rem & 31;
    const float* src = prev_eta + (size_t)bz * SS * SS;
    short* dst = peT + (size_t)bz * SS * SS;
    int r0 = cy * 64, c0 = cx * 64;
    #pragma unroll
    for (int p = 0; p < 4; ++p) {
      int id2 = tid + p * 256, r = id2 >> 4, c4 = (id2 & 15) << 2;
      float4 v = *(const float4*)(src + (size_t)(r0 + r) * SS + c0 + c4);
      t[r][c4] = v.x; t[r][c4+1] = v.y; t[r][c4+2] = v.z; t[r][c4+3] = v.w;
    }
    __syncthreads();
    #pragma unroll
    for (int p = 0; p < 4; ++p) {
      int id2 = tid + p * 256, c = id2 >> 4, r4 = (id2 & 15) << 2;
      s16x4 o;
      o[0] = f2b(t[r4][c]); o[1] = f2b(t[r4+1][c]); o[2] = f2b(t[r4+2][c]); o[3] = f2b(t[r4+3][c]);
      *(s16x4*)(dst + (size_t)(c0 + c) * SS + r0 + r4) = o;
    }
    return;
  }
  // band zero: the 64x64 region above each even diagonal tile of etaL
  {
    int idx = bid - 6156;
    int u = idx & 15, b = idx >> 4;
    int q0 = u * 128, c0 = q0 + 64;
    size_t base = (size_t)b * SS * SS;
    int r = tid >> 2, c = (tid & 3) * 16;
    s16x8 z = {};
    *(s16x8*)(etaL + base + (size_t)(q0 + r) * SS + c0 + c) = z;
    *(s16x8*)(etaL + base + (size_t)(q0 + r) * SS + c0 + c + 8) = z;
  }
}

// ---------------- transpose V per (b,h) + fused ||v||_2 ----------------
__global__ __launch_bounds__(256) void transpose_v_k(const short* __restrict__ Vq, short* __restrict__ Vt,
                                                     float* __restrict__ vmag) {
  __shared__ short t[64][72];
  int bh = blockIdx.y, s0 = blockIdx.x * 64;
  int b = bh >> 4, h = bh & 15;
  const short* src = Vq + ((size_t)(b * SS + s0)) * LDQ + h * 64;
  short* dst = Vt + ((size_t)bh * 64) * SS + s0;
  int tid = threadIdx.x;
  #pragma unroll
  for (int p = 0; p < 2; ++p) {
    int idx = tid + p * 256, r = idx >> 3, c8 = (idx & 7) << 3;
    s16x8 v = *(const s16x8*)(src + (size_t)r * LDQ + c8);
    *(s16x8*)&t[r][c8] = v;
  }
  __syncthreads();
  #pragma unroll
  for (int p = 0; p < 2; ++p) {
    int idx = tid + p * 256, d = idx >> 3, s8 = (idx & 7) << 3;
    s16x8 o;
    #pragma unroll
    for (int j = 0; j < 8; ++j) o[j] = t[s8 + j][d];
    *(s16x8*)(dst + (size_t)d * SS + s8) = o;
  }
  int row = tid >> 2, part = tid & 3;
  float acc = 0.f;
  #pragma unroll
  for (int j = 0; j < 16; ++j) { float v = b2f(t[row][part * 16 + j]); acc += v * v; }
  acc += __shfl_xor(acc, 1);
  acc += __shfl_xor(acc, 2);
  if (part == 0) vmag[(size_t)bh * SS + s0 + row] = sqrtf(acc);
}

// ---------------- QKV GEMM (R13-proven): 128x128 tile, BK=32, 8 waves, XCD-swizzled ----------------
__global__ __launch_bounds__(512) void gemm_qkv_k(
    const short* __restrict__ A, const short* __restrict__ Bt, short* __restrict__ C,
    const float* __restrict__ bias, int M, int N, int K)
{
  __shared__ short As[2][128 * 32];
  __shared__ short Bs[2][128 * 32];
  int bx = blockIdx.x, by = blockIdx.y;
  {
    int lin = bx + gridDim.x * by;
    int nwg = gridDim.x * gridDim.y;
    int q = nwg >> 3;
    int sw = (lin & 7) * q + (lin >> 3);
    bx = sw % gridDim.x; by = sw / gridDim.x;
  }
  int m0 = by * 128, n0 = bx * 128;
  int tid = threadIdx.x, w = tid >> 6, l = tid & 63;
  int wm = w >> 2, wn = w & 3;
  f32x4 acc[4][2] = {};
  const int scol = ((l & 3) ^ ((l >> 3) & 3)) * 8;
  const short* aSrc = A + (size_t)(m0 + w * 16 + (l >> 2)) * K + scol;
  const short* bSrc = Bt + (size_t)(n0 + w * 16 + (l >> 2)) * K + scol;
  int ar = wm * 64 + (l & 15);
  int br = wn * 32 + (l & 15);
  const int koffr = ((l >> 4) ^ ((l >> 1) & 3)) * 8;
  auto STAGE = [&](int buf, int k0) {
    async16(&As[buf][w * 512], aSrc + k0);
    async16(&Bs[buf][w * 512], bSrc + k0);
  };
  STAGE(0, 0);
  int cur = 0;
  for (int k0 = 0; k0 < K; k0 += 32) {
    __syncthreads();
    if (k0 + 32 < K) STAGE(cur ^ 1, k0 + 32);
    const short* AB = As[cur];
    const short* BBs = Bs[cur];
    s16x8 af[4], bfr[2];
    #pragma unroll
    for (int m = 0; m < 4; ++m) af[m] = *(const s16x8*)(AB + (ar + m * 16) * 32 + koffr);
    #pragma unroll
    for (int n = 0; n < 2; ++n) bfr[n] = *(const s16x8*)(BBs + (br + n * 16) * 32 + koffr);
    __builtin_amdgcn_s_setprio(1);
    #pragma unroll
    for (int m = 0; m < 4; ++m)
      #pragma unroll
      for (int n = 0; n < 2; ++n)
        acc[m][n] = mfma16(af[m], bfr[n], acc[m][n]);
    __builtin_amdgcn_s_setprio(0);
    cur ^= 1;
  }
  int wr = m0 + wm * 64, wc = n0 + wn * 32;
  int rsub = (l >> 4) * 4, csub = l & 15;
  #pragma unroll
  for (int m = 0; m < 4; ++m)
    #pragma unroll
    for (int n = 0; n < 2; ++n) {
      int col = wc + n * 16 + csub;
      float bv = bias[col];
      #pragma unroll
      for (int r = 0; r < 4; ++r) {
        int row = wr + m * 16 + rsub + r;
        C[(size_t)row * N + col] = f2b(acc[m][n][r] + bv);
      }
    }
}

// ---------------- 64-col 8-wave GEMM body, BK=64, async16 double-buffered (R17-proven) ----------------
template<bool HAS_BIAS>
DI void gemm64(const short* __restrict__ A, const short* __restrict__ B,
               float* __restrict__ C, const float* __restrict__ bias,
               int m0, int n0, int kmax, int K, int N,
               short (*As)[128 * 64], short (*Bs)[64 * 64], int tid)
{
  int w = tid >> 6, l = tid & 63;
  int wm = w >> 2, wn = w & 3;
  f32x4 acc[4] = {};
  const int swz = ((l & 7) ^ ((l >> 3) & 7)) * 8;
  const short* aSrc = A + (size_t)(m0 + w * 16 + (l >> 3)) * K + swz;
  const short* bSrc = B + (size_t)(n0 + w * 8 + (l >> 3)) * K + swz;
  int ar = wm * 64 + (l & 15);
  int br = wn * 16 + (l & 15);
  const int c0 = (((l >> 4) + 0) ^ (l & 7)) * 8;
  const int c1 = (((l >> 4) + 4) ^ (l & 7)) * 8;
  auto STAGE = [&](int buf, int k0) {
    async16(&As[buf][(2 * w) * 512],     aSrc + k0);
    async16(&As[buf][(2 * w + 1) * 512], aSrc + (size_t)8 * K + k0);
    async16(&Bs[buf][w * 512],           bSrc + k0);
  };
  __syncthreads();              // guard LDS reuse across phases
  STAGE(0, 0);
  int cur = 0;
  for (int k0 = 0; k0 < kmax; k0 += 64) {
    __syncthreads();
    if (k0 + 64 < kmax) STAGE(cur ^ 1, k0 + 64);
    const short* AB = As[cur];
    const short* BBs = Bs[cur];
    s16x8 af0[4], af1[4];
    #pragma unroll
    for (int m = 0; m < 4; ++m) {
      af0[m] = *(const s16x8*)(AB + (ar + m * 16) * 64 + c0);
      af1[m] = *(const s16x8*)(AB + (ar + m * 16) * 64 + c1);
    }
    s16x8 bf0 = *(const s16x8*)(BBs + br * 64 + c0);
    s16x8 bf1 = *(const s16x8*)(BBs + br * 64 + c1);
    __builtin_amdgcn_s_setprio(1);
    #pragma unroll
    for (int m = 0; m < 4; ++m) acc[m] = mfma16(af0[m], bf0, acc[m]);
    #pragma unroll
    for (int m = 0; m < 4; ++m) acc[m] = mfma16(af1[m], bf1, acc[m]);
    __builtin_amdgcn_s_setprio(0);
    cur ^= 1;
  }
  int wr = m0 + wm * 64, wc = n0 + wn * 16;
  int rsub = (l >> 4) * 4, csub = l & 15;
  int col = wc + csub;
  float bv = HAS_BIAS ? bias[col] : 0.f;
  #pragma unroll
  for (int m = 0; m < 4; ++m)
    #pragma unroll
    for (int r = 0; r < 4; ++r) {
      int row = wr + m * 16 + rsub + r;
      C[(size_t)row * N + col] = acc[m][r] + bv;
    }
}

// ---------------- tail: fused {causal eta GEMM (uniform pair blocks)} + {output projection} ----------------
// Natural blockIdx mapping: same-bx blocks (sharing the dominant peT B-panel) land on the same
// XCD (32 % 8 == 0), giving accidental-but-correct B-panel L2 affinity. Do not remap.
__global__ __launch_bounds__(512) void tail_k(
    const short* __restrict__ etaL, const short* __restrict__ peT, float* __restrict__ out1,
    const short* __restrict__ Om, const short* __restrict__ Wob, float* __restrict__ out0,
    const float* __restrict__ bo)
{
  __shared__ short As[2][128 * 64];
  __shared__ short Bs[2][64 * 64];
  int tid = threadIdx.x;
  if (blockIdx.z == 0) {
    int b = blockIdx.y & 1, p = blockIdx.y >> 1;
    int n0 = blockIdx.x * 64;
    const short* A = etaL + (size_t)b * SS * SS;
    const short* B = peT + (size_t)b * SS * SS;
    float* C = out1 + (size_t)b * SS * SS;
    gemm64<false>(A, B, C, nullptr, p * 128, n0, (p + 1) * 128, SS, SS, As, Bs, tid);
    gemm64<false>(A, B, C, nullptr, (15 - p) * 128, n0, (16 - p) * 128, SS, SS, As, Bs, tid);
  } else {
    gemm64<true>(Om, Wob, out0, bo, blockIdx.x * 128, blockIdx.y * 64, DD, DD, DD, As, Bs, tid);
  }
}

// ---------------- flash attention fwd: swapped QK^T, fixed-m, split-K, reg-staged K/V dbuf (80 KB, 1 barrier/iter) ----------------
__global__ __launch_bounds__(512) void flash_k(
    const short* __restrict__ Q, const short* __restrict__ Kk, const short* __restrict__ Vt,
    short* __restrict__ Om, float* __restrict__ lstat)
{
  __shared__ short Ks[2][2][64 * 64];   // [group][buf]
  __shared__ short Vs[2][2][64 * 64];
  __shared__ short Ps[8][16 * 64];
  int bh = blockIdx.x, p = blockIdx.y;
  int b = bh >> 4, h = bh & 15;
  int tid = threadIdx.x, w = tid >> 6, l = tid & 63;
  int g = w >> 2, wq = w & 3;
  int qtB = 31 - p;
  int myqt = g ? qtB : p;
  int koff = (l >> 4) * 8;
  const short* qbase = Q + ((size_t)(b * SS)) * LDQ + h * 64 + koff;
  int qrow = myqt * 64 + wq * 16 + (l & 15);
  s16x8 aq0 = *(const s16x8*)(qbase + (size_t)qrow * LDQ);
  s16x8 aq1 = *(const s16x8*)(qbase + (size_t)qrow * LDQ + 32);
  s16x8 onesf;
  #pragma unroll
  for (int j = 0; j < 8; ++j) onesf[j] = (short)0x3F80;  // bf16 1.0
  f32x4 o[4] = {};
  f32x4 lacc = {};
  const int swz = ((l & 7) ^ (l >> 3)) * 8;
  const short* kSrc = Kk + ((size_t)(b * SS) + wq * 16 + (l >> 3)) * LDQ + h * 64 + swz;
  const short* vSrc = Vt + ((size_t)bh * 64 + wq * 16 + (l >> 3)) * SS + swz;
  const int c0 = (((l >> 4) + 0) ^ (l & 7)) * 8;
  const int c1 = (((l >> 4) + 4) ^ (l & 7)) * 8;
  const int prow = l & 15;
  const int pwithin = ((l >> 4) & 1) * 4;
  auto tileof = [&](int it) { return g == 0 ? it : (it <= p ? it : 15 + it - p); };
  s16x8 kr0, kr1, vr0, vr1;
  auto LOADR = [&](int t) {
    kr0 = *(const s16x8*)(kSrc + (size_t)t * 64 * LDQ);
    kr1 = *(const s16x8*)(kSrc + (size_t)t * 64 * LDQ + (size_t)8 * LDQ);
    vr0 = *(const s16x8*)(vSrc + t * 64);
    vr1 = *(const s16x8*)(vSrc + t * 64 + (size_t)8 * SS);
  };
  auto WRITE = [&](int buf) {
    *(s16x8*)&Ks[g][buf][(2 * wq) * 512 + l * 8]     = kr0;
    *(s16x8*)&Ks[g][buf][(2 * wq + 1) * 512 + l * 8] = kr1;
    *(s16x8*)&Vs[g][buf][(2 * wq) * 512 + l * 8]     = vr0;
    *(s16x8*)&Vs[g][buf][(2 * wq + 1) * 512 + l * 8] = vr1;
  };
  const int nit = g ? 17 : 16;
  LOADR(tileof(0));
  WRITE(0);
  if (nit > 1) LOADR(tileof(1));
  __syncthreads();
  int cur = 0;
  for (int it = 0; it < 17; ++it) {
    if (it < nit) {
      if (it + 1 < nit) {
        WRITE(cur ^ 1);
        if (it + 2 < nit) LOADR(tileof(it + 2));
      }
      int t = tileof(it);
      const short* KB = Ks[g][cur];
      const short* VB = Vs[g][cur];
      f32x4 s[4] = {};
      __builtin_amdgcn_s_setprio(1);
      #pragma unroll
      for (int n = 0; n < 4; ++n) {
        int row = n * 16 + (l & 15);
        s16x8 bk0 = *(const s16x8*)(KB + row * 64 + c0);
        s16x8 bk1 = *(const s16x8*)(KB + row * 64 + c1);
        s[n] = mfma16(bk0, aq0, s[n]);   // swapped: D[kv][q]
        s[n] = mfma16(bk1, aq1, s[n]);
      }
      __builtin_amdgcn_s_setprio(0);
      if (t == myqt) {     // diagonal tile: causal mask (S^T indices)
        int ql = wq * 16 + (l & 15);
        #pragma unroll
        for (int n = 0; n < 4; ++n)
          #pragma unroll
          for (int r = 0; r < 4; ++r) {
            int kv = n * 16 + (l >> 4) * 4 + r;
            if (kv > ql) s[n][r] = -1e30f;
          }
      }
      #pragma unroll
      for (int n = 0; n < 4; ++n) {
        short* dst = &Ps[w][prow * 64 + (((2 * n + ((l >> 4) >> 1)) ^ (l & 7)) << 3) + pwithin];
        #pragma unroll
        for (int r = 0; r < 4; ++r)
          dst[r] = f2b(__builtin_amdgcn_exp2f(__builtin_fmaf(s[n][r], ALPHA2, -8.0f)));
      }
      __builtin_amdgcn_s_setprio(1);
      #pragma unroll
      for (int st = 0; st < 2; ++st) {
        int pc = (((st * 4) + (l >> 4)) ^ (l & 7)) * 8;
        s16x8 ap = *(const s16x8*)(&Ps[w][(l & 15) * 64 + pc]);
        lacc = mfma16(ap, onesf, lacc);          // row-sum of P via matrix pipe
        #pragma unroll
        for (int n = 0; n < 4; ++n) {
          int row = n * 16 + (l & 15);
          s16x8 bv = *(const s16x8*)(VB + row * 64 + pc);
          o[n] = mfma16(ap, bv, o[n]);
        }
      }
      __builtin_amdgcn_s_setprio(0);
      if (g == 0 && it == p) {
        #pragma unroll
        for (int r = 0; r < 4; ++r) {
          float inv = 1.0f / lacc[r];
          int qr = p * 64 + wq * 16 + (l >> 4) * 4 + r;
          #pragma unroll
          for (int n = 0; n < 4; ++n)
            Om[((size_t)(b * SS + qr)) * DD + h * 64 + n * 16 + (l & 15)] = f2b(o[n][r] * inv);
          if ((l & 15) == 0) lstat[(size_t)bh * SS + qr] = lacc[r];
        }
        #pragma unroll
        for (int n = 0; n < 4; ++n) o[n] = f32x4{0.f, 0.f, 0.f, 0.f};
        lacc = f32x4{0.f, 0.f, 0.f, 0.f};
        myqt = qtB;
        qrow = qtB * 64 + wq * 16 + (l & 15);
        aq0 = *(const s16x8*)(qbase + (size_t)qrow * LDQ);
        aq1 = *(const s16x8*)(qbase + (size_t)qrow * LDQ + 32);
      }
    }
    __syncthreads();   // single barrier: publishes buf[cur^1] writes, retires buf[cur] reads
    cur ^= 1;
  }
  float* Oex = (float*)&Ks[0][0][0];   // 16 KB = group-0's two K buffers (retired)
  float* Lex = (float*)&Vs[0][0][0];
  if (g == 0) {
    #pragma unroll
    for (int n = 0; n < 4; ++n)
      #pragma unroll
      for (int r = 0; r < 4; ++r)
        Oex[wq * 1024 + ((l >> 4) * 4 + r) * 64 + n * 16 + (l & 15)] = o[n][r];
    #pragma unroll
    for (int r = 0; r < 4; ++r)
      Lex[wq * 64 + (l >> 4) * 4 + r] = lacc[r];
  }
  __syncthreads();
  if (g == 1) {
    #pragma unroll
    for (int r = 0; r < 4; ++r) {
      float lt = lacc[r] + Lex[wq * 64 + (l >> 4) * 4 + r];
      float inv = 1.0f / lt;
      int qr = qtB * 64 + wq * 16 + (l >> 4) * 4 + r;
      #pragma unroll
      for (int n = 0; n < 4; ++n) {
        float ot = o[n][r] + Oex[wq * 1024 + ((l >> 4) * 4 + r) * 64 + n * 16 + (l & 15)];
        Om[((size_t)(b * SS + qr)) * DD + h * 64 + n * 16 + (l & 15)] = f2b(ot * inv);
      }
      if ((l & 15) == 0) lstat[(size_t)bh * SS + qr] = lt;
    }
  }
}

// ---------------- eta_layer (A' = I + eta_layer): T14 reg-staged single-buffer Ks (24 KB -> 6 blocks/CU) ----------------
__global__ __launch_bounds__(256) void eta_k(
    const short* __restrict__ Q, const short* __restrict__ Kk,
    const float* __restrict__ lstat, const float* __restrict__ vmag, short* __restrict__ etaL)
{
  __shared__ short Ks[64 * 128];
  __shared__ float lrlL[16][64], lvmL[16][64];
  int idx = blockIdx.x, b = blockIdx.y;
  int qt = (int)((sqrtf(8.f * idx + 1.f) - 1.f) * 0.5f);
  while ((qt + 1) * (qt + 2) / 2 <= idx) ++qt;
  while (qt * (qt + 1) / 2 > idx) --qt;
  int kt = idx - qt * (qt + 1) / 2;
  int q0 = qt * 64, k0 = kt * 64;
  bool diag = (kt == qt);
  int tid = threadIdx.x, w = tid >> 6, l = tid & 63;
  int qrA = q0 + w * 16 + (l & 15);
  f32x4 eta[4] = {};
  const short* kRow[4];
  #pragma unroll
  for (int j = 0; j < 4; ++j) {
    int rj = (4 * w + j) * 4 + (l >> 4);
    int kp = (l & 8) | ((l & 7) ^ (rj & 7));
    kRow[j] = Kk + ((size_t)(b * SS + k0 + rj)) * LDQ + kp * 8;
  }
  s16x8 kreg[4];
  #pragma unroll
  for (int j = 0; j < 4; ++j) kreg[j] = *(const s16x8*)(kRow[j]);   // head-pair 0
  {
    int hh = tid >> 4, jj = (tid & 15) * 4;
    size_t base = (size_t)(b * HH + hh) * SS;
    float4 lv = *(const float4*)(lstat + base + q0 + jj);
    float4 rv;
    rv.x = -__log2f(lv.x) - 8.f; rv.y = -__log2f(lv.y) - 8.f;
    rv.z = -__log2f(lv.z) - 8.f; rv.w = -__log2f(lv.w) - 8.f;
    *(float4*)&lrlL[hh][jj] = rv;
    float4 vv = *(const float4*)(vmag + base + k0 + jj);
    float4 wv;
    wv.x = __log2f(vv.x); wv.y = __log2f(vv.y);
    wv.z = __log2f(vv.z); wv.w = __log2f(vv.w);
    *(float4*)&lvmL[hh][jj] = wv;
  }
  const short* qbase = Q + ((size_t)(b * SS + qrA)) * LDQ + (l >> 4) * 8;
  s16x8 aq0 = *(const s16x8*)(qbase);        // head 0 fragments
  s16x8 aq1 = *(const s16x8*)(qbase + 32);
  for (int hp = 0; hp < 8; ++hp) {
    __syncthreads();                         // prior phase's Ks reads complete
    #pragma unroll
    for (int j = 0; j < 4; ++j)
      *(s16x8*)&Ks[(w * 4 + j) * 512 + l * 8] = kreg[j];
    if (hp < 7) {
      #pragma unroll
      for (int j = 0; j < 4; ++j) kreg[j] = *(const s16x8*)(kRow[j] + (hp + 1) * 128);
    }
    __syncthreads();                         // Ks ready
    #pragma unroll
    for (int hd = 0; hd < 2; ++hd) {
      int h = 2 * hp + hd;
      s16x8 nq0 = aq0, nq1 = aq1;
      if (h < 15) {
        nq0 = *(const s16x8*)(qbase + (h + 1) * 64);
        nq1 = *(const s16x8*)(qbase + (h + 1) * 64 + 32);
      }
      const int cc0 = (hd * 8 + ((l >> 4) ^ (l & 7))) * 8;
      const int cc1 = (hd * 8 + (((l >> 4) + 4) ^ (l & 7))) * 8;
      f32x4 s[4] = {};
      __builtin_amdgcn_s_setprio(1);
      #pragma unroll
      for (int n = 0; n < 4; ++n) {
        int row = n * 16 + (l & 15);
        s16x8 bk0 = *(const s16x8*)(Ks + row * 128 + cc0);
        s16x8 bk1 = *(const s16x8*)(Ks + row * 128 + cc1);
        s[n] = mfma16(aq0, bk0, s[n]);
        s[n] = mfma16(aq1, bk1, s[n]);
      }
      __builtin_amdgcn_s_setprio(0);
      float rl[4];
      #pragma unroll
      for (int r = 0; r < 4; ++r) rl[r] = lrlL[h][w * 16 + (l >> 4) * 4 + r];
      #pragma unroll
      for (int n = 0; n < 4; ++n) {
        float vm = lvmL[h][n * 16 + (l & 15)];
        #pragma unroll
        for (int r = 0; r < 4; ++r) {
          float pr = __builtin_amdgcn_exp2f(__builtin_fmaf(s[n][r], ALPHA2, vm + rl[r]));
          if (diag) {
            int kv = k0 + n * 16 + (l & 15), qr = q0 + w * 16 + (l >> 4) * 4 + r;
            if (kv > qr) pr = 0.f;
          }
          eta[n][r] += pr;
        }
      }
      aq0 = nq0; aq1 = nq1;
    }
  }
  #pragma unroll
  for (int n = 0; n < 4; ++n) {
    int kv = k0 + n * 16 + (l & 15);
    #pragma unroll
    for (int r = 0; r < 4; ++r) {
      int qr = q0 + w * 16 + (l >> 4) * 4 + r;
      float v = eta[n][r];
      if (diag && kv == qr) v += 1.0f;   // A' = I + eta_layer (residual folded into GEMM)
      etaL[((size_t)(b * SS + qr)) * SS + kv] = f2b(v);
    }
  }
}

extern "C" void kernel_launch(void* const* d_in, const int* in_sizes, int n_in,
                              void* d_out, int out_size, void* d_ws, size_t ws_size,
                              hipStream_t stream) {
  const float* x        = (const float*)d_in[0];
  const float* prev_eta = (const float*)d_in[1];
  const float* Wq = (const float*)d_in[3];
  const float* bq = (const float*)d_in[4];
  const float* Wk = (const float*)d_in[5];
  const float* bk = (const float*)d_in[6];
  const float* Wv = (const float*)d_in[7];
  const float* bv = (const float*)d_in[8];
  const float* Wo = (const float*)d_in[9];
  const float* bo = (const float*)d_in[10];
  float* out0 = (float*)d_out;
  float* out1 = out0 + TOK * DD;

  char* p = (char*)d_ws;
  auto alloc = [&](size_t bytes) { char* r = p; p += (bytes + 255) & ~(size_t)255; return r; };
  short* Xb   = (short*)alloc(TOK * DD * 2);
  short* Wcat = (short*)alloc((size_t)3 * DD * DD * 2);
  short* Wob  = (short*)alloc((size_t)DD * DD * 2);
  float* bcat = (float*)alloc((size_t)3 * DD * 4);
  short* QKV  = (short*)alloc(TOK * (size_t)LDQ * 2);
  short* Vtb  = (short*)alloc(TOK * DD * 2);
  short* Om   = (short*)alloc(TOK * DD * 2);
  short* peT  = (short*)alloc((size_t)BB * SS * SS * 2);
  short* etaL = (short*)alloc((size_t)BB * SS * SS * 2);
  float* lst  = (float*)alloc((size_t)BB * HH * SS * 4);
  float* vmg  = (float*)alloc((size_t)BB * HH * SS * 4);

  // 1) single fused prep launch (casts + biases + prev_eta transpose + band zero)
  prep2_k<<<6188, 256, 0, stream>>>(x, Wq, Wk, Wv, Wo, bq, bk, bv, prev_eta,
                                    Xb, Wcat, Wob, bcat, peT, etaL);

  // 2) fused QKV projection: BK=32, 8-wave blocks (R13-proven), XCD-swizzled (nwg=768)
  gemm_qkv_k<<<dim3(3 * DD / 128, TOK / 128, 1), 512, 0, stream>>>(
      Xb, Wcat, QKV, bcat, (int)TOK, 3 * DD, DD);

  // 3) V transpose + fused ||v||
  transpose_v_k<<<dim3(SS / 64, BB * HH), 256, 0, stream>>>(QKV + 2 * DD, Vtb, vmg);

  // 4) flash attention + l stats (split-K, swapped QK^T, reg-staged K/V dbuf, 1 barrier/iter)
  flash_k<<<dim3(32, 16), 512, 0, stream>>>(QKV, QKV + DD, Vtb, Om, lst);

  // 5) eta_layer (A' = I + eta_layer), T14 reg-staged, 6 blocks/CU
  eta_k<<<dim3(528, BB), 256, 0, stream>>>(QKV, QKV + DD, lst, vmg, etaL);

  // 6+7) fused tail: causal eta GEMM + output projection (natural mapping: B-panel XCD-affine)
  tail_k<<<dim3(32, 16, 2), 512, 0, stream>>>(etaL, peT, out1, Om, Wob, out0, bo);
}